// Round 1
// baseline (1701.342 us; speedup 1.0000x reference)
//
#include <hip/hip_runtime.h>
#include <hip/hip_bf16.h>
#include <stdint.h>

#define SEQ     4096
#define DMODEL  2048
#define NHEADS  16
#define DHEAD   128
#define QBLK    64
#define CHUNK   128
#define NCHUNK  (SEQ / CHUNK)

typedef __bf16 bf16_t;
typedef bf16_t bf16x8 __attribute__((ext_vector_type(8)));
typedef bf16_t bf16x4 __attribute__((ext_vector_type(4)));
typedef float  f32x4  __attribute__((ext_vector_type(4)));

// Flash attention, faithful to the reference quirks:
//   - total score scale = 1/128 (pre-scale * post-divide)
//   - p = exp(s - m_chunk)   [chunk-local max, NOT running max]
//   - o,l rescaled by exp(m_run_old - m_new); out = o / (l + 1e-6)
// Chunks of 128 keys processed strictly in order 0..31.
__global__ __launch_bounds__(256, 2)
void fa_fwd(const float* __restrict__ qg, const float* __restrict__ kg,
            const float* __restrict__ vg, float* __restrict__ og)
{
  __shared__ bf16_t Kl[CHUNK * DHEAD];  // 32 KB, swizzled [key][dh]; overlaid with P after QK^T
  __shared__ bf16_t Vt[DHEAD * CHUNK];  // 32 KB, swizzled [dh][key] (V transposed)

  const int tid  = threadIdx.x;
  const int wave = tid >> 6;
  const int lane = tid & 63;
  const int l15  = lane & 15;
  const int lhi  = lane >> 4;           // 0..3
  const int b    = blockIdx.z;
  const int h    = blockIdx.y;
  const int qrow0 = blockIdx.x * QBLK + wave * 16;

  // ---- Q fragments, A-operand layout (row = l15, k = lhi*8 + i), scaled by 1/128
  bf16x8 qa[4];
  {
    const float* qp = qg + ((size_t)(b * SEQ + qrow0 + l15)) * DMODEL + h * DHEAD;
    const float sc = 1.0f / 128.0f;
#pragma unroll
    for (int kb = 0; kb < 4; ++kb) {
      const float* p8 = qp + kb * 32 + lhi * 8;
      float4 x0 = *(const float4*)p8;
      float4 x1 = *(const float4*)(p8 + 4);
      bf16x8 a;
      a[0] = (bf16_t)(x0.x * sc); a[1] = (bf16_t)(x0.y * sc);
      a[2] = (bf16_t)(x0.z * sc); a[3] = (bf16_t)(x0.w * sc);
      a[4] = (bf16_t)(x1.x * sc); a[5] = (bf16_t)(x1.y * sc);
      a[6] = (bf16_t)(x1.z * sc); a[7] = (bf16_t)(x1.w * sc);
      qa[kb] = a;
    }
  }

  f32x4 oacc[8];
#pragma unroll
  for (int nt = 0; nt < 8; ++nt) { f32x4 z = {0.f, 0.f, 0.f, 0.f}; oacc[nt] = z; }
  float m_run[4] = {-INFINITY, -INFINITY, -INFINITY, -INFINITY};
  float l_run[4] = {0.f, 0.f, 0.f, 0.f};

  const float* kbp = kg + ((size_t)b * SEQ) * DMODEL + h * DHEAD;
  const float* vbp = vg + ((size_t)b * SEQ) * DMODEL + h * DHEAD;

  const int krow8 = tid >> 5;           // K staging: row within pass (0..7)
  const int kc4   = (tid & 31) * 4;     // K staging: dh col (x4 floats)
  const int vdh   = tid & 127;          // V staging: dh column
  const int vkg   = (tid >> 7) * 8;     // V staging: key sub-block (0 or 8)

  for (int c = 0; c < NCHUNK; ++c) {
    const int key0 = c * CHUNK;

    // ---- stage K chunk: bf16 [key][dh], XOR-swizzle byte ^= (key&7)<<4
#pragma unroll
    for (int pass = 0; pass < 16; ++pass) {
      const int key = pass * 8 + krow8;
      const float4 x = *(const float4*)(kbp + (size_t)(key0 + key) * DMODEL + kc4);
      bf16x4 y;
      y[0] = (bf16_t)x.x; y[1] = (bf16_t)x.y; y[2] = (bf16_t)x.z; y[3] = (bf16_t)x.w;
      const uint32_t byte = ((uint32_t)(key * 256 + kc4 * 2)) ^ ((key & 7) << 4);
      *(bf16x4*)((char*)Kl + byte) = y;
    }
    // ---- stage V chunk transposed: bf16 [dh][key], XOR-swizzle byte ^= (dh&7)<<4
#pragma unroll
    for (int it = 0; it < 8; ++it) {
      const int kb0 = it * 16 + vkg;
      const float* vp = vbp + (size_t)(key0 + kb0) * DMODEL + vdh;
      bf16x8 y;
#pragma unroll
      for (int j = 0; j < 8; ++j) y[j] = (bf16_t)vp[(size_t)j * DMODEL];
      const uint32_t byte = ((uint32_t)(vdh * 256 + kb0 * 2)) ^ ((vdh & 7) << 4);
      *(bf16x8*)((char*)Vt + byte) = y;
    }
    __syncthreads();

    // ---- S = Q K^T   (wave: 16 q-rows x 128 keys; 8 key-tiles x 4 k-steps)
    f32x4 sacc[8];
#pragma unroll
    for (int nt = 0; nt < 8; ++nt) {
      f32x4 acc = {0.f, 0.f, 0.f, 0.f};
      const int key = nt * 16 + l15;
#pragma unroll
      for (int kb = 0; kb < 4; ++kb) {
        const uint32_t byte =
            ((uint32_t)(key * 256 + (kb * 32 + lhi * 8) * 2)) ^ ((key & 7) << 4);
        bf16x8 bfr = *(const bf16x8*)((const char*)Kl + byte);
        acc = __builtin_amdgcn_mfma_f32_16x16x32_bf16(qa[kb], bfr, acc, 0, 0, 0);
      }
      sacc[nt] = acc;
    }

    // ---- chunk-local row max over 128 keys (reduce 8 tiles, then 16-lane group)
    float mc[4];
#pragma unroll
    for (int r = 0; r < 4; ++r) {
      float m0 = sacc[0][r];
#pragma unroll
      for (int nt = 1; nt < 8; ++nt) m0 = fmaxf(m0, sacc[nt][r]);
      mc[r] = m0;
    }
#pragma unroll
    for (int sh = 1; sh < 16; sh <<= 1)
#pragma unroll
      for (int r = 0; r < 4; ++r)
        mc[r] = fmaxf(mc[r], __shfl_xor(mc[r], sh, 64));

    float esc[4], psum[4];
#pragma unroll
    for (int r = 0; r < 4; ++r) {
      const float mn = fmaxf(m_run[r], mc[r]);
      esc[r] = __expf(m_run[r] - mn);   // exp(-inf)=0 handles first chunk
      m_run[r] = mn;
      psum[r] = 0.f;
    }

    // ---- p = exp(s - m_chunk), row-sum, convert to bf16
    bf16_t pb[32];
#pragma unroll
    for (int nt = 0; nt < 8; ++nt)
#pragma unroll
      for (int r = 0; r < 4; ++r) {
        const float p = __expf(sacc[nt][r] - mc[r]);
        psum[r] += p;
        pb[nt * 4 + r] = (bf16_t)p;
      }
#pragma unroll
    for (int sh = 1; sh < 16; sh <<= 1)
#pragma unroll
      for (int r = 0; r < 4; ++r)
        psum[r] += __shfl_xor(psum[r], sh, 64);
#pragma unroll
    for (int r = 0; r < 4; ++r)
      l_run[r] = l_run[r] * esc[r] + psum[r];
#pragma unroll
    for (int nt = 0; nt < 8; ++nt) {
      f32x4 o = oacc[nt];
      o[0] *= esc[0]; o[1] *= esc[1]; o[2] *= esc[2]; o[3] *= esc[3];
      oacc[nt] = o;
    }

    __syncthreads();  // all waves done reading Kl -> safe to overlay P

    // ---- P -> per-wave LDS slice (A-fragment-friendly [row16][key128], swizzled)
    bf16_t* Pw = Kl + wave * (16 * 128);
#pragma unroll
    for (int nt = 0; nt < 8; ++nt)
#pragma unroll
      for (int r = 0; r < 4; ++r) {
        const int row = lhi * 4 + r;
        const uint32_t byte =
            ((uint32_t)(row * 256 + (nt * 16 + l15) * 2)) ^ ((row & 7) << 4);
        *(bf16_t*)((char*)Pw + byte) = pb[nt * 4 + r];
      }
    asm volatile("s_waitcnt lgkmcnt(0)" ::: "memory");  // wave-local write->read ordering

    // ---- O += P V   (A = P from LDS, B = V^T fragments from Vt)
#pragma unroll
    for (int kb = 0; kb < 4; ++kb) {
      const uint32_t pbyte =
          ((uint32_t)(l15 * 256 + (kb * 32 + lhi * 8) * 2)) ^ ((l15 & 7) << 4);
      bf16x8 pf = *(const bf16x8*)((const char*)Pw + pbyte);
#pragma unroll
      for (int nt = 0; nt < 8; ++nt) {
        const int dh = nt * 16 + l15;
        const uint32_t vbyte =
            ((uint32_t)(dh * 256 + (kb * 32 + lhi * 8) * 2)) ^ ((dh & 7) << 4);
        bf16x8 vf = *(const bf16x8*)((const char*)Vt + vbyte);
        oacc[nt] = __builtin_amdgcn_mfma_f32_16x16x32_bf16(pf, vf, oacc[nt], 0, 0, 0);
      }
    }
    __syncthreads();  // before next chunk overwrites Kl/Vt
  }

  // ---- epilogue: out = O / (l + eps)
#pragma unroll
  for (int nt = 0; nt < 8; ++nt)
#pragma unroll
    for (int r = 0; r < 4; ++r) {
      const int row = lhi * 4 + r;
      const float val = oacc[nt][r] / (l_run[r] + 1e-6f);
      og[((size_t)(b * SEQ + qrow0 + row)) * DMODEL + h * DHEAD + nt * 16 + l15] = val;
    }
}

extern "C" void kernel_launch(void* const* d_in, const int* in_sizes, int n_in,
                              void* d_out, int out_size, void* d_ws, size_t ws_size,
                              hipStream_t stream) {
  const float* q = (const float*)d_in[0];
  const float* k = (const float*)d_in[1];
  const float* v = (const float*)d_in[2];
  float* o = (float*)d_out;
  const int B = in_sizes[0] / (SEQ * DMODEL);
  dim3 grid(SEQ / QBLK, NHEADS, B);
  fa_fwd<<<grid, 256, 0, stream>>>(q, k, v, o);
}